// Round 3
// baseline (6149.233 us; speedup 1.0000x reference)
//
#include <hip/hip_runtime.h>
#include <stdint.h>

#pragma clang fp contract(off)

#define T_STEPS 784
#define NH 64
#define NOUT 10

// One wave per batch row; lane = neuron index j (same lane reused for all 3 layers).
// All state in registers. Spike communication via __ballot (wave-uniform 64-bit mask).
//
// Numerical contract: replicate float32-numpy evaluation of the reference bit-exactly.
//  - state updates: each op individually rounded, Python left-to-right order
//    (contract(off) forbids fma fusion).
//  - s @ W.T: spikes are 0/1 so every product is EXACT; BLAS sgemm accumulates
//    ascending-k into one accumulator -> fma chain k=0..63 starting from 0.0f,
//    bias added afterwards as a separately-rounded op.  __fmaf_rn(s_k, w_k, acc)
//    with s_k in {0.0f, 1.0f} gives round(acc + exact_product): identical rounding.

__device__ __forceinline__ float bitf(uint32_t m, int k) {
    return ((m >> k) & 1u) ? 1.0f : 0.0f;   // wave-uniform -> SALU select
}

__global__ __launch_bounds__(256, 2) void tesnn_main_kernel(
    const float* __restrict__ input,
    const float* __restrict__ W1, const float* __restrict__ b1,
    const float* __restrict__ W2, const float* __restrict__ b2,
    const float* __restrict__ W3, const float* __restrict__ b3,
    const float* __restrict__ Wo, const float* __restrict__ bo,
    const float* __restrict__ ce,
    float* __restrict__ out, int N)
{
    const int lane = threadIdx.x & 63;
    const int wid = threadIdx.x >> 6;
    const int n = __builtin_amdgcn_readfirstlane(blockIdx.x * 4 + wid);
    if (n >= N) return;

    // ---- per-lane weights (lane = neuron j) ----
    const float w1 = W1[lane];          // W1 is [64][1]
    const float bb1 = b1[lane];
    const float bb2 = b2[lane];
    const float bb3 = b3[lane];

    float w2row[64], w3row[64];         // row j of W2 / W3, in VGPRs
#pragma unroll
    for (int q = 0; q < 16; ++q) {
        float4 a = ((const float4*)W2)[lane * 16 + q];
        w2row[4 * q + 0] = a.x; w2row[4 * q + 1] = a.y;
        w2row[4 * q + 2] = a.z; w2row[4 * q + 3] = a.w;
        float4 b = ((const float4*)W3)[lane * 16 + q];
        w3row[4 * q + 0] = b.x; w3row[4 * q + 1] = b.y;
        w3row[4 * q + 2] = b.z; w3row[4 * q + 3] = b.w;
    }

    // ---- state ----
    float m1 = 0.0f, t1 = 0.5f; bool s1 = false;
    float m2 = 0.0f, t2 = 0.5f; bool s2 = false;
    float m3 = 0.0f, t3 = 0.5f; bool s3 = false;
    float c3f = 0.0f;                   // layer-3 spike count (integer-valued, exact)

    const float* xrow = input + (size_t)n * T_STEPS;        // wave-uniform -> s_load
    const float* cerow = ce + (size_t)lane * T_STEPS;       // ce is [H][T]; per-lane row

    // software pipeline: x (uniform) and co (per-lane) one step ahead
    float x_cur = xrow[0];
    float co_cur = cerow[0];

#pragma unroll 1
    for (int t = 0; t < T_STEPS; ++t) {
        const int tn = (t < T_STEPS - 1) ? (t + 1) : (T_STEPS - 1);
        const float x_nxt = xrow[tn];
        const float co_nxt = cerow[tn];

        const float x = x_cur;
        const float co = co_cur;

        // ================= layer 1 =================
        // th = (th + mem*co) - ((th - 0.5)*0.02)   [each op rounded, old mem]
        {
            const float p = m1 * co;
            const float q = t1 + p;
            const float r = t1 - 0.5f;
            const float rs = r * 0.02f;
            t1 = q - rs;
        }
        // h1 = round(x*W1j) then + b1 (separate rounding, as np matmul + bias add)
        {
            const float h1p = x * w1;
            const float h1 = h1p + bb1;
            const float md = m1 * 0.5f;                 // exact
            const float keep = s1 ? 0.0f : md;          // mem*DECAY*(1-spike), exact
            m1 = keep + h1;
        }
        const bool p1 = m1 > t1;
        s1 = p1;
        const unsigned long long mk1 = __ballot(p1);
        const uint32_t m1lo = (uint32_t)mk1, m1hi = (uint32_t)(mk1 >> 32);

        // ================= layer 2 =================
        {
            const float p = m2 * co;
            const float q = t2 + p;
            const float r = t2 - 0.5f;
            const float rs = r * 0.02f;
            t2 = q - rs;
        }
        {
            float acc = 0.0f;
#pragma unroll
            for (int k = 0; k < 32; ++k) acc = __fmaf_rn(bitf(m1lo, k), w2row[k], acc);
#pragma unroll
            for (int k = 0; k < 32; ++k) acc = __fmaf_rn(bitf(m1hi, k), w2row[32 + k], acc);
            const float h2 = acc + bb2;
            const float md = m2 * 0.5f;
            const float keep = s2 ? 0.0f : md;
            m2 = keep + h2;
        }
        const bool p2 = m2 > t2;
        s2 = p2;
        const unsigned long long mk2 = __ballot(p2);
        const uint32_t m2lo = (uint32_t)mk2, m2hi = (uint32_t)(mk2 >> 32);

        // ================= layer 3 =================
        {
            const float p = m3 * co;
            const float q = t3 + p;
            const float r = t3 - 0.5f;
            const float rs = r * 0.02f;
            t3 = q - rs;
        }
        {
            float acc = 0.0f;
#pragma unroll
            for (int k = 0; k < 32; ++k) acc = __fmaf_rn(bitf(m2lo, k), w3row[k], acc);
#pragma unroll
            for (int k = 0; k < 32; ++k) acc = __fmaf_rn(bitf(m2hi, k), w3row[32 + k], acc);
            const float h3 = acc + bb3;
            const float md = m3 * 0.5f;
            const float keep = s3 ? 0.0f : md;
            m3 = keep + h3;
        }
        const bool p3 = m3 > t3;
        s3 = p3;
        c3f += p3 ? 1.0f : 0.0f;

        x_cur = x_nxt;
        co_cur = co_nxt;
    }

    // ---- epilogue: out[n][o] = (sum_t s3) @ Wo.T / T + bo ----
    // Output path does not feed back into the dynamics; f64 here is within
    // ~1e-5 of np's f32 step-accumulated osum, far under threshold.
    const double c3 = (double)c3f;
    double res = 0.0;
#pragma unroll
    for (int o = 0; o < NOUT; ++o) {
        double v = c3 * (double)Wo[o * NH + lane];
#pragma unroll
        for (int off = 32; off; off >>= 1) v += __shfl_xor(v, off, 64);
        if (lane == o) res = v;
    }
    if (lane < NOUT)
        out[(size_t)n * NOUT + lane] = (float)(res / (double)T_STEPS + (double)bo[lane]);
}

extern "C" void kernel_launch(void* const* d_in, const int* in_sizes, int n_in,
                              void* d_out, int out_size, void* d_ws, size_t ws_size,
                              hipStream_t stream) {
    const float* input = (const float*)d_in[0];
    const float* W1 = (const float*)d_in[1];
    const float* b1 = (const float*)d_in[2];
    const float* W2 = (const float*)d_in[3];
    const float* b2 = (const float*)d_in[4];
    const float* W3 = (const float*)d_in[5];
    const float* b3 = (const float*)d_in[6];
    const float* Wo = (const float*)d_in[7];
    const float* bo = (const float*)d_in[8];
    const float* ce = (const float*)d_in[9];
    float* out = (float*)d_out;

    const int N = in_sizes[0] / T_STEPS;

    hipLaunchKernelGGL(tesnn_main_kernel,
                       dim3((N + 3) / 4), dim3(256), 0, stream,
                       input, W1, b1, W2, b2, W3, b3, Wo, bo, ce, out, N);
}

// Round 4
// 6095.974 us; speedup vs baseline: 1.0087x; 1.0087x over previous
//
#include <hip/hip_runtime.h>
#include <stdint.h>

#pragma clang fp contract(off)

#define T_STEPS 784
#define NH 64
#define NOUT 10

// One wave (block=64) per batch row; lane = neuron index j.
// All weights in named scalar VGPRs (no arrays -> no scratch demotion).
// Spike broadcast via v_readlane of the spike float (exactly 0.0f/1.0f),
// preserving the bit-exact ascending-k fma accumulation order that matches
// the float32-numpy reference (proven in round 3: absmax 9.8e-4).

#define REP64(M) \
  M(0) M(1) M(2) M(3) M(4) M(5) M(6) M(7) \
  M(8) M(9) M(10) M(11) M(12) M(13) M(14) M(15) \
  M(16) M(17) M(18) M(19) M(20) M(21) M(22) M(23) \
  M(24) M(25) M(26) M(27) M(28) M(29) M(30) M(31) \
  M(32) M(33) M(34) M(35) M(36) M(37) M(38) M(39) \
  M(40) M(41) M(42) M(43) M(44) M(45) M(46) M(47) \
  M(48) M(49) M(50) M(51) M(52) M(53) M(54) M(55) \
  M(56) M(57) M(58) M(59) M(60) M(61) M(62) M(63)

__device__ __forceinline__ float rlane(uint32_t v, int k) {
    return __uint_as_float((uint32_t)__builtin_amdgcn_readlane((int)v, k));
}

__global__ __launch_bounds__(64, 2) void tesnn_main_kernel(
    const float* __restrict__ input,
    const float* __restrict__ W1, const float* __restrict__ b1,
    const float* __restrict__ W2, const float* __restrict__ b2,
    const float* __restrict__ W3, const float* __restrict__ b3,
    const float* __restrict__ Wo, const float* __restrict__ bo,
    const float* __restrict__ ce,
    float* __restrict__ out, int N)
{
    const int lane = threadIdx.x;
    const int n = blockIdx.x;
    if (n >= N) return;

    // ---- per-lane weights (lane = neuron j), all named scalars ----
    const float w1 = W1[lane];          // W1 is [64][1]
    const float bb1 = b1[lane];
    const float bb2 = b2[lane];
    const float bb3 = b3[lane];

#define LDW(k) \
    const float w2_##k = W2[(size_t)lane * NH + k]; \
    const float w3_##k = W3[(size_t)lane * NH + k];
    REP64(LDW)
#undef LDW

    // ---- state ----
    float m1 = 0.0f, t1 = 0.5f; bool s1 = false;
    float m2 = 0.0f, t2 = 0.5f; bool s2 = false;
    float m3 = 0.0f, t3 = 0.5f; bool s3 = false;
    float c3f = 0.0f;                   // layer-3 spike count (integer, exact)

    const float* xrow = input + (size_t)n * T_STEPS;     // wave-uniform
    const float* cerow = ce + (size_t)lane * T_STEPS;    // ce is [H][T]

    float x_cur = xrow[0];
    float co_cur = cerow[0];

#pragma unroll 1
    for (int t = 0; t < T_STEPS; ++t) {
        const int tn = (t < T_STEPS - 1) ? (t + 1) : (T_STEPS - 1);
        const float x_nxt = xrow[tn];
        const float co_nxt = cerow[tn];

        const float x = x_cur;
        const float co = co_cur;

        // ================= layer 1 =================
        {
            const float p = m1 * co;
            const float q = t1 + p;
            const float r = t1 - 0.5f;
            const float rs = r * 0.02f;
            t1 = q - rs;
        }
        {
            const float h1p = x * w1;        // np matmul: single product, rounded
            const float h1 = h1p + bb1;      // bias add, separately rounded
            const float md = m1 * 0.5f;
            const float keep = s1 ? 0.0f : md;
            m1 = keep + h1;
        }
        const bool p1 = m1 > t1;
        const float s1f = p1 ? 1.0f : 0.0f;
        s1 = p1;
        const uint32_t s1u = __float_as_uint(s1f);

        // ================= layer 2 =================
        {
            const float p = m2 * co;
            const float q = t2 + p;
            const float r = t2 - 0.5f;
            const float rs = r * 0.02f;
            t2 = q - rs;
        }
        {
            float acc = 0.0f;
#define F2(k) acc = __fmaf_rn(rlane(s1u, k), w2_##k, acc);
            REP64(F2)
#undef F2
            const float h2 = acc + bb2;
            const float md = m2 * 0.5f;
            const float keep = s2 ? 0.0f : md;
            m2 = keep + h2;
        }
        const bool p2 = m2 > t2;
        const float s2f = p2 ? 1.0f : 0.0f;
        s2 = p2;
        const uint32_t s2u = __float_as_uint(s2f);

        // ================= layer 3 =================
        {
            const float p = m3 * co;
            const float q = t3 + p;
            const float r = t3 - 0.5f;
            const float rs = r * 0.02f;
            t3 = q - rs;
        }
        {
            float acc = 0.0f;
#define F3(k) acc = __fmaf_rn(rlane(s2u, k), w3_##k, acc);
            REP64(F3)
#undef F3
            const float h3 = acc + bb3;
            const float md = m3 * 0.5f;
            const float keep = s3 ? 0.0f : md;
            m3 = keep + h3;
        }
        const bool p3 = m3 > t3;
        s3 = p3;
        c3f += p3 ? 1.0f : 0.0f;

        x_cur = x_nxt;
        co_cur = co_nxt;
    }

    // ---- epilogue: out[n][o] = (sum_t s3) @ Wo.T / T + bo ----
    const double c3 = (double)c3f;
    double res = 0.0;
#pragma unroll
    for (int o = 0; o < NOUT; ++o) {
        double v = c3 * (double)Wo[o * NH + lane];
#pragma unroll
        for (int off = 32; off; off >>= 1) v += __shfl_xor(v, off, 64);
        if (lane == o) res = v;
    }
    if (lane < NOUT)
        out[(size_t)n * NOUT + lane] = (float)(res / (double)T_STEPS + (double)bo[lane]);
}

extern "C" void kernel_launch(void* const* d_in, const int* in_sizes, int n_in,
                              void* d_out, int out_size, void* d_ws, size_t ws_size,
                              hipStream_t stream) {
    const float* input = (const float*)d_in[0];
    const float* W1 = (const float*)d_in[1];
    const float* b1 = (const float*)d_in[2];
    const float* W2 = (const float*)d_in[3];
    const float* b2 = (const float*)d_in[4];
    const float* W3 = (const float*)d_in[5];
    const float* b3 = (const float*)d_in[6];
    const float* Wo = (const float*)d_in[7];
    const float* bo = (const float*)d_in[8];
    const float* ce = (const float*)d_in[9];
    float* out = (float*)d_out;

    const int N = in_sizes[0] / T_STEPS;

    hipLaunchKernelGGL(tesnn_main_kernel,
                       dim3(N), dim3(64), 0, stream,
                       input, W1, b1, W2, b2, W3, b3, Wo, bo, ce, out, N);
}

// Round 5
// 5892.436 us; speedup vs baseline: 1.0436x; 1.0345x over previous
//
#include <hip/hip_runtime.h>
#include <stdint.h>

#pragma clang fp contract(off)

#define T_STEPS 784
#define NH 64
#define NOUT 10

// One wave (block=64) per batch row; lane = neuron index j.
// Weights in named scalars (compiler places in VGPR/AGPR unified file).
// Spike selection moved to the SCALAR pipe: ballot mask is wave-uniform, so
// sel_k = ((mask>>k)&1) * 0x3F800000 is computed on SALU (co-issues with VALU)
// and feeds v_fmac_f32 acc, s_sel, v_w  -- exactly one VALU op per k.
// Multiplier is exactly 0.0f/1.0f -> products exact -> the fma chain rounds
// bit-identically to rounds 3/4 (proven absmax 9.8e-4 vs np-f32 reference).

#define REP32LO(M) \
  M(0) M(1) M(2) M(3) M(4) M(5) M(6) M(7) \
  M(8) M(9) M(10) M(11) M(12) M(13) M(14) M(15) \
  M(16) M(17) M(18) M(19) M(20) M(21) M(22) M(23) \
  M(24) M(25) M(26) M(27) M(28) M(29) M(30) M(31)

#define REP32HI(M) \
  M(32) M(33) M(34) M(35) M(36) M(37) M(38) M(39) \
  M(40) M(41) M(42) M(43) M(44) M(45) M(46) M(47) \
  M(48) M(49) M(50) M(51) M(52) M(53) M(54) M(55) \
  M(56) M(57) M(58) M(59) M(60) M(61) M(62) M(63)

__global__ __launch_bounds__(64, 2) void tesnn_main_kernel(
    const float* __restrict__ input,
    const float* __restrict__ W1, const float* __restrict__ b1,
    const float* __restrict__ W2, const float* __restrict__ b2,
    const float* __restrict__ W3, const float* __restrict__ b3,
    const float* __restrict__ Wo, const float* __restrict__ bo,
    const float* __restrict__ ce,
    float* __restrict__ out, int N)
{
    const int lane = threadIdx.x;
    const int n = blockIdx.x;
    if (n >= N) return;

    // ---- per-lane weights (lane = neuron j), all named scalars ----
    const float w1 = W1[lane];          // W1 is [64][1]
    const float bb1 = b1[lane];
    const float bb2 = b2[lane];
    const float bb3 = b3[lane];

#define LDW(k) \
    const float w2_##k = W2[(size_t)lane * NH + k]; \
    const float w3_##k = W3[(size_t)lane * NH + k];
    REP32LO(LDW) REP32HI(LDW)
#undef LDW

    // ---- state ----
    float m1 = 0.0f, t1 = 0.5f; bool s1 = false;
    float m2 = 0.0f, t2 = 0.5f; bool s2 = false;
    float m3 = 0.0f, t3 = 0.5f; bool s3 = false;
    float c3f = 0.0f;                   // layer-3 spike count (integer, exact)

    const float* xrow = input + (size_t)n * T_STEPS;     // wave-uniform
    const float* cerow = ce + (size_t)lane * T_STEPS;    // ce is [H][T]

    float x_cur = xrow[0];
    float co_cur = cerow[0];

#pragma unroll 1
    for (int t = 0; t < T_STEPS; ++t) {
        const int tn = (t < T_STEPS - 1) ? (t + 1) : (T_STEPS - 1);
        const float x_nxt = xrow[tn];
        const float co_nxt = cerow[tn];

        const float x = x_cur;
        const float co = co_cur;

        // ================= layer 1 =================
        {
            const float p = m1 * co;
            const float q = t1 + p;
            const float r = t1 - 0.5f;
            const float rs = r * 0.02f;
            t1 = q - rs;
        }
        {
            const float h1p = x * w1;        // np matmul: single product, rounded
            const float h1 = h1p + bb1;      // bias add, separately rounded
            const float md = m1 * 0.5f;
            const float keep = s1 ? 0.0f : md;
            m1 = keep + h1;
        }
        const bool p1 = m1 > t1;
        s1 = p1;
        const unsigned long long mk1 = __ballot(p1);
        const uint32_t lo1 = (uint32_t)mk1, hi1 = (uint32_t)(mk1 >> 32);

        // ================= layer 2 =================
        {
            const float p = m2 * co;
            const float q = t2 + p;
            const float r = t2 - 0.5f;
            const float rs = r * 0.02f;
            t2 = q - rs;
        }
        {
            float acc = 0.0f;
            // sel computed on SALU (uniform), fmac on VALU: 1 VALU per k.
#define F2L(k) { const float sel = __uint_as_float(((lo1 >> (k)) & 1u) * 0x3F800000u); \
                 acc = __fmaf_rn(sel, w2_##k, acc); }
#define F2H(k) { const float sel = __uint_as_float(((hi1 >> ((k) - 32)) & 1u) * 0x3F800000u); \
                 acc = __fmaf_rn(sel, w2_##k, acc); }
            REP32LO(F2L)
            REP32HI(F2H)
#undef F2L
#undef F2H
            const float h2 = acc + bb2;
            const float md = m2 * 0.5f;
            const float keep = s2 ? 0.0f : md;
            m2 = keep + h2;
        }
        const bool p2 = m2 > t2;
        s2 = p2;
        const unsigned long long mk2 = __ballot(p2);
        const uint32_t lo2 = (uint32_t)mk2, hi2 = (uint32_t)(mk2 >> 32);

        // ================= layer 3 =================
        {
            const float p = m3 * co;
            const float q = t3 + p;
            const float r = t3 - 0.5f;
            const float rs = r * 0.02f;
            t3 = q - rs;
        }
        {
            float acc = 0.0f;
#define F3L(k) { const float sel = __uint_as_float(((lo2 >> (k)) & 1u) * 0x3F800000u); \
                 acc = __fmaf_rn(sel, w3_##k, acc); }
#define F3H(k) { const float sel = __uint_as_float(((hi2 >> ((k) - 32)) & 1u) * 0x3F800000u); \
                 acc = __fmaf_rn(sel, w3_##k, acc); }
            REP32LO(F3L)
            REP32HI(F3H)
#undef F3L
#undef F3H
            const float h3 = acc + bb3;
            const float md = m3 * 0.5f;
            const float keep = s3 ? 0.0f : md;
            m3 = keep + h3;
        }
        const bool p3 = m3 > t3;
        s3 = p3;
        c3f += p3 ? 1.0f : 0.0f;

        x_cur = x_nxt;
        co_cur = co_nxt;
    }

    // ---- epilogue: out[n][o] = (sum_t s3) @ Wo.T / T + bo ----
    const double c3 = (double)c3f;
    double res = 0.0;
#pragma unroll
    for (int o = 0; o < NOUT; ++o) {
        double v = c3 * (double)Wo[o * NH + lane];
#pragma unroll
        for (int off = 32; off; off >>= 1) v += __shfl_xor(v, off, 64);
        if (lane == o) res = v;
    }
    if (lane < NOUT)
        out[(size_t)n * NOUT + lane] = (float)(res / (double)T_STEPS + (double)bo[lane]);
}

extern "C" void kernel_launch(void* const* d_in, const int* in_sizes, int n_in,
                              void* d_out, int out_size, void* d_ws, size_t ws_size,
                              hipStream_t stream) {
    const float* input = (const float*)d_in[0];
    const float* W1 = (const float*)d_in[1];
    const float* b1 = (const float*)d_in[2];
    const float* W2 = (const float*)d_in[3];
    const float* b2 = (const float*)d_in[4];
    const float* W3 = (const float*)d_in[5];
    const float* b3 = (const float*)d_in[6];
    const float* Wo = (const float*)d_in[7];
    const float* bo = (const float*)d_in[8];
    const float* ce = (const float*)d_in[9];
    float* out = (float*)d_out;

    const int N = in_sizes[0] / T_STEPS;

    hipLaunchKernelGGL(tesnn_main_kernel,
                       dim3(N), dim3(64), 0, stream,
                       input, W1, b1, W2, b2, W3, b3, Wo, bo, ce, out, N);
}

// Round 6
// 3624.525 us; speedup vs baseline: 1.6966x; 1.6257x over previous
//
#include <hip/hip_runtime.h>
#include <stdint.h>

#pragma clang fp contract(off)

#define T_STEPS 784
#define NH 64
#define NOUT 10

// One wave (block=64) per batch row; lane = neuron index j.
// Spike broadcast via LDS: each layer writes its 64-lane spike vector
// (exact 0.0f/1.0f) with one ds_write_b32, then all lanes read it back with
// uniform-address ds_read_b128 (hardware broadcast, conflict-free, DS pipe
// runs parallel to VALU). The dot product is then 1 VALU fmac per k with the
// exact ascending-k single-accumulator bias-last order proven in rounds 3-5
// (absmax 9.77e-4) -- arithmetic is bit-identical to those rounds.

__global__ __launch_bounds__(64, 2) void tesnn_main_kernel(
    const float* __restrict__ input,
    const float* __restrict__ W1, const float* __restrict__ b1,
    const float* __restrict__ W2, const float* __restrict__ b2,
    const float* __restrict__ W3, const float* __restrict__ b3,
    const float* __restrict__ Wo, const float* __restrict__ bo,
    const float* __restrict__ ce,
    float* __restrict__ out, int N)
{
    __shared__ float sA[NH];   // layer-1 spike vector (one wave per block)
    __shared__ float sB[NH];   // layer-2 spike vector

    const int lane = threadIdx.x;
    const int n = blockIdx.x;
    if (n >= N) return;

    // ---- per-lane weights (lane = neuron j); full unroll -> VGPR/AGPR file ----
    const float w1 = W1[lane];          // W1 is [64][1]
    const float bb1 = b1[lane];
    const float bb2 = b2[lane];
    const float bb3 = b3[lane];

    float w2row[64], w3row[64];
#pragma unroll
    for (int q = 0; q < 16; ++q) {
        float4 a = ((const float4*)W2)[lane * 16 + q];
        w2row[4 * q + 0] = a.x; w2row[4 * q + 1] = a.y;
        w2row[4 * q + 2] = a.z; w2row[4 * q + 3] = a.w;
        float4 b = ((const float4*)W3)[lane * 16 + q];
        w3row[4 * q + 0] = b.x; w3row[4 * q + 1] = b.y;
        w3row[4 * q + 2] = b.z; w3row[4 * q + 3] = b.w;
    }

    // ---- state ----
    float m1 = 0.0f, t1 = 0.5f; bool s1 = false;
    float m2 = 0.0f, t2 = 0.5f; bool s2 = false;
    float m3 = 0.0f, t3 = 0.5f; bool s3 = false;
    float c3f = 0.0f;                   // layer-3 spike count (integer, exact)

    const float* xrow = input + (size_t)n * T_STEPS;     // wave-uniform
    const float* cerow = ce + (size_t)lane * T_STEPS;    // ce is [H][T]

    float x_cur = xrow[0];
    float co_cur = cerow[0];

#pragma unroll 1
    for (int t = 0; t < T_STEPS; ++t) {
        const int tn = (t < T_STEPS - 1) ? (t + 1) : (T_STEPS - 1);
        const float x_nxt = xrow[tn];
        const float co_nxt = cerow[tn];

        const float x = x_cur;
        const float co = co_cur;

        // ================= layer 1 =================
        {
            const float p = m1 * co;
            const float q = t1 + p;
            const float r = t1 - 0.5f;
            const float rs = r * 0.02f;
            t1 = q - rs;
        }
        {
            const float h1p = x * w1;        // np matmul: single product, rounded
            const float h1 = h1p + bb1;      // bias add, separately rounded
            const float md = m1 * 0.5f;
            const float keep = s1 ? 0.0f : md;
            m1 = keep + h1;
        }
        const bool p1 = m1 > t1;
        s1 = p1;
        sA[lane] = p1 ? 1.0f : 0.0f;         // ds_write_b32 (exact 0/1)

        // ================= layer 2 =================
        {   // th update first: VALU work covers the LDS write->read latency
            const float p = m2 * co;
            const float q = t2 + p;
            const float r = t2 - 0.5f;
            const float rs = r * 0.02f;
            t2 = q - rs;
        }
        {
            float acc = 0.0f;
#pragma unroll
            for (int g = 0; g < 16; ++g) {
                const float4 q4 = *reinterpret_cast<const float4*>(&sA[4 * g]); // uniform addr -> broadcast
                acc = __fmaf_rn(q4.x, w2row[4 * g + 0], acc);
                acc = __fmaf_rn(q4.y, w2row[4 * g + 1], acc);
                acc = __fmaf_rn(q4.z, w2row[4 * g + 2], acc);
                acc = __fmaf_rn(q4.w, w2row[4 * g + 3], acc);
            }
            const float h2 = acc + bb2;
            const float md = m2 * 0.5f;
            const float keep = s2 ? 0.0f : md;
            m2 = keep + h2;
        }
        const bool p2 = m2 > t2;
        s2 = p2;
        sB[lane] = p2 ? 1.0f : 0.0f;

        // ================= layer 3 =================
        {
            const float p = m3 * co;
            const float q = t3 + p;
            const float r = t3 - 0.5f;
            const float rs = r * 0.02f;
            t3 = q - rs;
        }
        {
            float acc = 0.0f;
#pragma unroll
            for (int g = 0; g < 16; ++g) {
                const float4 q4 = *reinterpret_cast<const float4*>(&sB[4 * g]);
                acc = __fmaf_rn(q4.x, w3row[4 * g + 0], acc);
                acc = __fmaf_rn(q4.y, w3row[4 * g + 1], acc);
                acc = __fmaf_rn(q4.z, w3row[4 * g + 2], acc);
                acc = __fmaf_rn(q4.w, w3row[4 * g + 3], acc);
            }
            const float h3 = acc + bb3;
            const float md = m3 * 0.5f;
            const float keep = s3 ? 0.0f : md;
            m3 = keep + h3;
        }
        const bool p3 = m3 > t3;
        s3 = p3;
        c3f += p3 ? 1.0f : 0.0f;

        x_cur = x_nxt;
        co_cur = co_nxt;
    }

    // ---- epilogue: out[n][o] = (sum_t s3) @ Wo.T / T + bo ----
    const double c3 = (double)c3f;
    double res = 0.0;
#pragma unroll
    for (int o = 0; o < NOUT; ++o) {
        double v = c3 * (double)Wo[o * NH + lane];
#pragma unroll
        for (int off = 32; off; off >>= 1) v += __shfl_xor(v, off, 64);
        if (lane == o) res = v;
    }
    if (lane < NOUT)
        out[(size_t)n * NOUT + lane] = (float)(res / (double)T_STEPS + (double)bo[lane]);
}

extern "C" void kernel_launch(void* const* d_in, const int* in_sizes, int n_in,
                              void* d_out, int out_size, void* d_ws, size_t ws_size,
                              hipStream_t stream) {
    const float* input = (const float*)d_in[0];
    const float* W1 = (const float*)d_in[1];
    const float* b1 = (const float*)d_in[2];
    const float* W2 = (const float*)d_in[3];
    const float* b2 = (const float*)d_in[4];
    const float* W3 = (const float*)d_in[5];
    const float* b3 = (const float*)d_in[6];
    const float* Wo = (const float*)d_in[7];
    const float* bo = (const float*)d_in[8];
    const float* ce = (const float*)d_in[9];
    float* out = (float*)d_out;

    const int N = in_sizes[0] / T_STEPS;

    hipLaunchKernelGGL(tesnn_main_kernel,
                       dim3(N), dim3(64), 0, stream,
                       input, W1, b1, W2, b2, W3, b3, Wo, bo, ce, out, N);
}

// Round 7
// 3623.395 us; speedup vs baseline: 1.6971x; 1.0003x over previous
//
#include <hip/hip_runtime.h>
#include <stdint.h>

#pragma clang fp contract(off)

#define T_STEPS 784
#define NH 64
#define NOUT 10

// One wave (block=64) per batch row; lane = neuron index j.
// Spike broadcast via LDS: each layer writes its 64-lane spike vector
// (exact 0.0f/1.0f) with one ds_write_b32, then all lanes read it back with
// uniform-address ds_read_b128 (hardware broadcast, conflict-free, DS pipe
// runs parallel to VALU). Dot product: 1 VALU fmac per k, exact ascending-k
// single-accumulator bias-last order (bit-identical to rounds 3-6, absmax
// 9.77e-4 vs np-f32 reference).
//
// __launch_bounds__(64,1): per-wave register budget 512 (arch cap 256) so the
// 128 weight scalars live in ARCH VGPRs. Round 6's (64,2) budget made LLVM
// demote them to AGPRs, costing ~128 v_accvgpr_read per step (measured:
// 315 VALU inst/step vs ~165 hand-counted).

__global__ __launch_bounds__(64, 1) void tesnn_main_kernel(
    const float* __restrict__ input,
    const float* __restrict__ W1, const float* __restrict__ b1,
    const float* __restrict__ W2, const float* __restrict__ b2,
    const float* __restrict__ W3, const float* __restrict__ b3,
    const float* __restrict__ Wo, const float* __restrict__ bo,
    const float* __restrict__ ce,
    float* __restrict__ out, int N)
{
    __shared__ float sA[NH];   // layer-1 spike vector (one wave per block)
    __shared__ float sB[NH];   // layer-2 spike vector

    const int lane = threadIdx.x;
    const int n = blockIdx.x;
    if (n >= N) return;

    // ---- per-lane weights (lane = neuron j); full unroll -> arch VGPRs ----
    const float w1 = W1[lane];          // W1 is [64][1]
    const float bb1 = b1[lane];
    const float bb2 = b2[lane];
    const float bb3 = b3[lane];

    float w2row[64], w3row[64];
#pragma unroll
    for (int q = 0; q < 16; ++q) {
        float4 a = ((const float4*)W2)[lane * 16 + q];
        w2row[4 * q + 0] = a.x; w2row[4 * q + 1] = a.y;
        w2row[4 * q + 2] = a.z; w2row[4 * q + 3] = a.w;
        float4 b = ((const float4*)W3)[lane * 16 + q];
        w3row[4 * q + 0] = b.x; w3row[4 * q + 1] = b.y;
        w3row[4 * q + 2] = b.z; w3row[4 * q + 3] = b.w;
    }

    // ---- state ----
    float m1 = 0.0f, t1 = 0.5f; bool s1 = false;
    float m2 = 0.0f, t2 = 0.5f; bool s2 = false;
    float m3 = 0.0f, t3 = 0.5f; bool s3 = false;
    float c3f = 0.0f;                   // layer-3 spike count (integer, exact)

    const float* xrow = input + (size_t)n * T_STEPS;     // wave-uniform
    const float* cerow = ce + (size_t)lane * T_STEPS;    // ce is [H][T]

    float x_cur = xrow[0];
    float co_cur = cerow[0];

#pragma unroll 1
    for (int t = 0; t < T_STEPS; ++t) {
        const int tn = (t < T_STEPS - 1) ? (t + 1) : (T_STEPS - 1);
        const float x_nxt = xrow[tn];
        const float co_nxt = cerow[tn];

        const float x = x_cur;
        const float co = co_cur;

        // ================= layer 1 =================
        {
            const float p = m1 * co;
            const float q = t1 + p;
            const float r = t1 - 0.5f;
            const float rs = r * 0.02f;
            t1 = q - rs;
        }
        {
            const float h1p = x * w1;        // np matmul: single product, rounded
            const float h1 = h1p + bb1;      // bias add, separately rounded
            const float md = m1 * 0.5f;
            const float keep = s1 ? 0.0f : md;
            m1 = keep + h1;
        }
        const bool p1 = m1 > t1;
        s1 = p1;
        sA[lane] = p1 ? 1.0f : 0.0f;         // ds_write_b32 (exact 0/1)

        // ================= layer 2 =================
        {   // th update first: VALU work covers the LDS write->read latency
            const float p = m2 * co;
            const float q = t2 + p;
            const float r = t2 - 0.5f;
            const float rs = r * 0.02f;
            t2 = q - rs;
        }
        {
            float acc = 0.0f;
#pragma unroll
            for (int g = 0; g < 16; ++g) {
                const float4 q4 = *reinterpret_cast<const float4*>(&sA[4 * g]); // uniform addr -> broadcast
                acc = __fmaf_rn(q4.x, w2row[4 * g + 0], acc);
                acc = __fmaf_rn(q4.y, w2row[4 * g + 1], acc);
                acc = __fmaf_rn(q4.z, w2row[4 * g + 2], acc);
                acc = __fmaf_rn(q4.w, w2row[4 * g + 3], acc);
            }
            const float h2 = acc + bb2;
            const float md = m2 * 0.5f;
            const float keep = s2 ? 0.0f : md;
            m2 = keep + h2;
        }
        const bool p2 = m2 > t2;
        s2 = p2;
        sB[lane] = p2 ? 1.0f : 0.0f;

        // ================= layer 3 =================
        {
            const float p = m3 * co;
            const float q = t3 + p;
            const float r = t3 - 0.5f;
            const float rs = r * 0.02f;
            t3 = q - rs;
        }
        {
            float acc = 0.0f;
#pragma unroll
            for (int g = 0; g < 16; ++g) {
                const float4 q4 = *reinterpret_cast<const float4*>(&sB[4 * g]);
                acc = __fmaf_rn(q4.x, w3row[4 * g + 0], acc);
                acc = __fmaf_rn(q4.y, w3row[4 * g + 1], acc);
                acc = __fmaf_rn(q4.z, w3row[4 * g + 2], acc);
                acc = __fmaf_rn(q4.w, w3row[4 * g + 3], acc);
            }
            const float h3 = acc + bb3;
            const float md = m3 * 0.5f;
            const float keep = s3 ? 0.0f : md;
            m3 = keep + h3;
        }
        const bool p3 = m3 > t3;
        s3 = p3;
        c3f += p3 ? 1.0f : 0.0f;

        x_cur = x_nxt;
        co_cur = co_nxt;
    }

    // ---- epilogue: out[n][o] = (sum_t s3) @ Wo.T / T + bo ----
    const double c3 = (double)c3f;
    double res = 0.0;
#pragma unroll
    for (int o = 0; o < NOUT; ++o) {
        double v = c3 * (double)Wo[o * NH + lane];
#pragma unroll
        for (int off = 32; off; off >>= 1) v += __shfl_xor(v, off, 64);
        if (lane == o) res = v;
    }
    if (lane < NOUT)
        out[(size_t)n * NOUT + lane] = (float)(res / (double)T_STEPS + (double)bo[lane]);
}

extern "C" void kernel_launch(void* const* d_in, const int* in_sizes, int n_in,
                              void* d_out, int out_size, void* d_ws, size_t ws_size,
                              hipStream_t stream) {
    const float* input = (const float*)d_in[0];
    const float* W1 = (const float*)d_in[1];
    const float* b1 = (const float*)d_in[2];
    const float* W2 = (const float*)d_in[3];
    const float* b2 = (const float*)d_in[4];
    const float* W3 = (const float*)d_in[5];
    const float* b3 = (const float*)d_in[6];
    const float* Wo = (const float*)d_in[7];
    const float* bo = (const float*)d_in[8];
    const float* ce = (const float*)d_in[9];
    float* out = (float*)d_out;

    const int N = in_sizes[0] / T_STEPS;

    hipLaunchKernelGGL(tesnn_main_kernel,
                       dim3(N), dim3(64), 0, stream,
                       input, W1, b1, W2, b2, W3, b3, Wo, bo, ce, out, N);
}

// Round 8
// 3524.440 us; speedup vs baseline: 1.7447x; 1.0281x over previous
//
#include <hip/hip_runtime.h>
#include <stdint.h>

#pragma clang fp contract(off)

#define T_STEPS 784
#define NH 64
#define NOUT 10

typedef __attribute__((ext_vector_type(2))) float f32x2;
typedef __attribute__((ext_vector_type(4))) float f32x4;

// v_pk_fma_f32: D.lo = fma(S0.lo, S1.sel, S2.lo), D.hi = fma(S0.hi, S1.sel, S2.hi)
// PK_LO: both halves use the LOW  dword of the weight pair (op_sel_hi[1]=0)
// PK_HI: both halves use the HIGH dword of the weight pair (op_sel[1]=1, op_sel_hi[1]=1)
// Each half is an independent IEEE round-to-nearest fma -> per-row chain is
// bit-identical to the scalar __fmaf_rn chain proven in rounds 3-7.
#define PK_LO(acc, s, wp) \
    asm("v_pk_fma_f32 %0, %1, %2, %0 op_sel:[0,0,0] op_sel_hi:[1,0,1]" \
        : "+v"(acc) : "v"(s), "v"(wp))
#define PK_HI(acc, s, wp) \
    asm("v_pk_fma_f32 %0, %1, %2, %0 op_sel:[0,1,0] op_sel_hi:[1,1,1]" \
        : "+v"(acc) : "v"(s), "v"(wp))

// Two batch rows per wave; lane = neuron index j.
// Spike broadcast via LDS float2 {row0, row1}; uniform-address b128 reads
// deliver two k's (two float2) per DS instruction.

__global__ __attribute__((amdgpu_flat_work_group_size(64, 64)))
__attribute__((amdgpu_waves_per_eu(2, 2)))
void tesnn_main_kernel(
    const float* __restrict__ input,
    const float* __restrict__ W1, const float* __restrict__ b1,
    const float* __restrict__ W2, const float* __restrict__ b2,
    const float* __restrict__ W3, const float* __restrict__ b3,
    const float* __restrict__ Wo, const float* __restrict__ bo,
    const float* __restrict__ ce,
    float* __restrict__ out, int N)
{
    __shared__ f32x2 sA2[NH];   // layer-1 spikes {row0, row1}
    __shared__ f32x2 sB2[NH];   // layer-2 spikes {row0, row1}

    const int lane = threadIdx.x;
    const int n0 = blockIdx.x * 2;
    if (n0 >= N) return;
    const int n1 = (n0 + 1 < N) ? (n0 + 1) : n0;   // duplicate last row if N odd

    // ---- per-lane weights (lane = neuron j) ----
    const float w1 = W1[lane];
    const float bb1 = b1[lane];
    const float bb2 = b2[lane];
    const float bb3 = b3[lane];

    f32x2 w2p[32], w3p[32];     // pairs {w[2i], w[2i+1]} of row j
#pragma unroll
    for (int i = 0; i < 32; ++i) {
        w2p[i] = *reinterpret_cast<const f32x2*>(&W2[(size_t)lane * NH + 2 * i]);
        w3p[i] = *reinterpret_cast<const f32x2*>(&W3[(size_t)lane * NH + 2 * i]);
    }

    // ---- state (a = row0, b = row1) ----
    float m1a = 0.0f, t1a = 0.5f; bool s1a = false;
    float m1b = 0.0f, t1b = 0.5f; bool s1b = false;
    float m2a = 0.0f, t2a = 0.5f; bool s2a = false;
    float m2b = 0.0f, t2b = 0.5f; bool s2b = false;
    float m3a = 0.0f, t3a = 0.5f;
    float m3b = 0.0f, t3b = 0.5f;
    bool s3a = false, s3b = false;
    float c3fa = 0.0f, c3fb = 0.0f;

    const float* xrow0 = input + (size_t)n0 * T_STEPS;   // wave-uniform
    const float* xrow1 = input + (size_t)n1 * T_STEPS;
    const float* cerow = ce + (size_t)lane * T_STEPS;    // ce is [H][T]

    float xa_cur = xrow0[0];
    float xb_cur = xrow1[0];
    float co_cur = cerow[0];

#pragma unroll 1
    for (int t = 0; t < T_STEPS; ++t) {
        const int tn = (t < T_STEPS - 1) ? (t + 1) : (T_STEPS - 1);
        const float xa_nxt = xrow0[tn];
        const float xb_nxt = xrow1[tn];
        const float co_nxt = cerow[tn];

        const float xa = xa_cur, xb = xb_cur, co = co_cur;

        // ================= layer 1 =================
        {   // th = (th + mem*co) - ((th-0.5)*0.02), each op rounded, old mem
            const float pa = m1a * co; const float qa = t1a + pa;
            const float ra = t1a - 0.5f; const float sa_ = ra * 0.02f; t1a = qa - sa_;
            const float pb = m1b * co; const float qb = t1b + pb;
            const float rb = t1b - 0.5f; const float sb_ = rb * 0.02f; t1b = qb - sb_;
        }
        {
            const float ha = (xa * w1) + bb1;           // product rounded, bias rounded
            const float mda = m1a * 0.5f;
            m1a = (s1a ? 0.0f : mda) + ha;
            const float hb = (xb * w1) + bb1;
            const float mdb = m1b * 0.5f;
            m1b = (s1b ? 0.0f : mdb) + hb;
        }
        const bool p1a = m1a > t1a; s1a = p1a;
        const bool p1b = m1b > t1b; s1b = p1b;
        {
            f32x2 sv; sv.x = p1a ? 1.0f : 0.0f; sv.y = p1b ? 1.0f : 0.0f;
            sA2[lane] = sv;                              // ds_write_b64
        }

        // ================= layer 2 =================
        {
            const float pa = m2a * co; const float qa = t2a + pa;
            const float ra = t2a - 0.5f; const float sa_ = ra * 0.02f; t2a = qa - sa_;
            const float pb = m2b * co; const float qb = t2b + pb;
            const float rb = t2b - 0.5f; const float sb_ = rb * 0.02f; t2b = qb - sb_;
        }
        {
            f32x2 acc; acc.x = 0.0f; acc.y = 0.0f;
#pragma unroll
            for (int g = 0; g < 32; ++g) {
                const f32x4 q = *reinterpret_cast<const f32x4*>(&sA2[2 * g]); // uniform b128
                f32x2 s0; s0.x = q.x; s0.y = q.y;        // spikes k=2g   {r0,r1}
                f32x2 s1; s1.x = q.z; s1.y = q.w;        // spikes k=2g+1 {r0,r1}
                PK_LO(acc, s0, w2p[g]);
                PK_HI(acc, s1, w2p[g]);
            }
            const float h2a = acc.x + bb2;
            const float mda = m2a * 0.5f;
            m2a = (s2a ? 0.0f : mda) + h2a;
            const float h2b = acc.y + bb2;
            const float mdb = m2b * 0.5f;
            m2b = (s2b ? 0.0f : mdb) + h2b;
        }
        const bool p2a = m2a > t2a; s2a = p2a;
        const bool p2b = m2b > t2b; s2b = p2b;
        {
            f32x2 sv; sv.x = p2a ? 1.0f : 0.0f; sv.y = p2b ? 1.0f : 0.0f;
            sB2[lane] = sv;
        }

        // ================= layer 3 =================
        {
            const float pa = m3a * co; const float qa = t3a + pa;
            const float ra = t3a - 0.5f; const float sa_ = ra * 0.02f; t3a = qa - sa_;
            const float pb = m3b * co; const float qb = t3b + pb;
            const float rb = t3b - 0.5f; const float sb_ = rb * 0.02f; t3b = qb - sb_;
        }
        {
            f32x2 acc; acc.x = 0.0f; acc.y = 0.0f;
#pragma unroll
            for (int g = 0; g < 32; ++g) {
                const f32x4 q = *reinterpret_cast<const f32x4*>(&sB2[2 * g]);
                f32x2 s0; s0.x = q.x; s0.y = q.y;
                f32x2 s1; s1.x = q.z; s1.y = q.w;
                PK_LO(acc, s0, w3p[g]);
                PK_HI(acc, s1, w3p[g]);
            }
            const float h3a = acc.x + bb3;
            const float mda = m3a * 0.5f;
            m3a = (s3a ? 0.0f : mda) + h3a;
            const float h3b = acc.y + bb3;
            const float mdb = m3b * 0.5f;
            m3b = (s3b ? 0.0f : mdb) + h3b;
        }
        const bool p3a = m3a > t3a; s3a = p3a;
        const bool p3b = m3b > t3b; s3b = p3b;
        c3fa += p3a ? 1.0f : 0.0f;
        c3fb += p3b ? 1.0f : 0.0f;

        xa_cur = xa_nxt; xb_cur = xb_nxt; co_cur = co_nxt;
    }

    // ---- epilogue: out[n][o] = (sum_t s3) @ Wo.T / T + bo (once per kernel) ----
    const double c3A = (double)c3fa;
    const double c3B = (double)c3fb;
    double resA = 0.0, resB = 0.0;
#pragma unroll
    for (int o = 0; o < NOUT; ++o) {
        const double wo = (double)Wo[o * NH + lane];
        double vA = c3A * wo;
        double vB = c3B * wo;
#pragma unroll
        for (int off = 32; off; off >>= 1) {
            vA += __shfl_xor(vA, off, 64);
            vB += __shfl_xor(vB, off, 64);
        }
        if (lane == o) { resA = vA; resB = vB; }
    }
    if (lane < NOUT) {
        out[(size_t)n0 * NOUT + lane] = (float)(resA / (double)T_STEPS + (double)bo[lane]);
        if (n1 != n0)
            out[(size_t)n1 * NOUT + lane] = (float)(resB / (double)T_STEPS + (double)bo[lane]);
    }
}

extern "C" void kernel_launch(void* const* d_in, const int* in_sizes, int n_in,
                              void* d_out, int out_size, void* d_ws, size_t ws_size,
                              hipStream_t stream) {
    const float* input = (const float*)d_in[0];
    const float* W1 = (const float*)d_in[1];
    const float* b1 = (const float*)d_in[2];
    const float* W2 = (const float*)d_in[3];
    const float* b2 = (const float*)d_in[4];
    const float* W3 = (const float*)d_in[5];
    const float* b3 = (const float*)d_in[6];
    const float* Wo = (const float*)d_in[7];
    const float* bo = (const float*)d_in[8];
    const float* ce = (const float*)d_in[9];
    float* out = (float*)d_out;

    const int N = in_sizes[0] / T_STEPS;

    hipLaunchKernelGGL(tesnn_main_kernel,
                       dim3((N + 1) / 2), dim3(64), 0, stream,
                       input, W1, b1, W2, b2, W3, b3, Wo, bo, ce, out, N);
}

// Round 9
// 3374.081 us; speedup vs baseline: 1.8225x; 1.0446x over previous
//
#include <hip/hip_runtime.h>
#include <stdint.h>

#pragma clang fp contract(off)

#define T_STEPS 784
#define NH 64
#define NOUT 10

typedef __attribute__((ext_vector_type(2))) float f32x2;
typedef __attribute__((ext_vector_type(4))) float f32x4;

// v_pk_fma_f32: D.lo = fma(S0.lo, S1.sel, S2.lo), D.hi = fma(S0.hi, S1.sel, S2.hi)
// PK_LO: both halves read the LOW  dword of the weight pair (k = 2g)
// PK_HI: both halves read the HIGH dword of the weight pair (k = 2g+1)
// Each half is an independent IEEE-rn fma -> per-row ascending-k chain is
// bit-identical to the scalar __fmaf_rn chain proven in rounds 3-8.
#define PK_LO(acc, s, wp) \
    asm("v_pk_fma_f32 %0, %1, %2, %0 op_sel:[0,0,0] op_sel_hi:[1,0,1]" \
        : "+v"(acc) : "v"(s), "v"(wp))
#define PK_HI(acc, s, wp) \
    asm("v_pk_fma_f32 %0, %1, %2, %0 op_sel:[0,1,0] op_sel_hi:[1,1,1]" \
        : "+v"(acc) : "v"(s), "v"(wp))

// th = (th + mem*co) - ((th-0.5)*0.02), each op rounded, old mem  (r3-verified)
#define THUP(tt, mm) { const float p_ = (mm) * co; const float q_ = (tt) + p_; \
    const float r_ = (tt) - 0.5f; const float rs_ = r_ * 0.02f; (tt) = q_ - rs_; }
// mem = (spike ? 0 : mem*0.5) + h   (r3-verified)
#define MEMUP(mm, ss, hh) { const float md_ = (mm) * 0.5f; \
    const float keep_ = (ss) ? 0.0f : md_; (mm) = keep_ + (hh); }

// Four batch rows per wave (two pk-pairs {a,b} and {c,d}); lane = neuron j.
// Weights (32+32 f32x2) live in the unified RF (AGPR half); each weight pair
// is copied out once per step and feeds BOTH pk-pairs -> copy tax amortized.
// Spike broadcast: one f32x4 {sa,sb,sc,sd} per neuron in LDS; a single
// uniform-address b128 read feeds all 4 rows for one k.

__global__ __attribute__((amdgpu_flat_work_group_size(64, 64)))
__attribute__((amdgpu_waves_per_eu(2)))
void tesnn_main_kernel(
    const float* __restrict__ input,
    const float* __restrict__ W1, const float* __restrict__ b1,
    const float* __restrict__ W2, const float* __restrict__ b2,
    const float* __restrict__ W3, const float* __restrict__ b3,
    const float* __restrict__ Wo, const float* __restrict__ bo,
    const float* __restrict__ ce,
    float* __restrict__ out, int N)
{
    __shared__ f32x4 sA4[NH];   // layer-1 spikes {a,b,c,d}
    __shared__ f32x4 sB4[NH];   // layer-2 spikes {a,b,c,d}

    const int lane = threadIdx.x;
    const int n0 = blockIdx.x * 4;
    if (n0 >= N) return;
    const int na = n0;
    const int nb = (n0 + 1 < N) ? n0 + 1 : N - 1;
    const int nc = (n0 + 2 < N) ? n0 + 2 : N - 1;
    const int nd = (n0 + 3 < N) ? n0 + 3 : N - 1;

    // ---- per-lane weights (lane = neuron j) ----
    const float w1 = W1[lane];
    const float bb1 = b1[lane];
    const float bb2 = b2[lane];
    const float bb3 = b3[lane];

    f32x2 w2p[32], w3p[32];     // pairs {w[2g], w[2g+1]} of row j
#pragma unroll
    for (int i = 0; i < 32; ++i) {
        w2p[i] = *reinterpret_cast<const f32x2*>(&W2[(size_t)lane * NH + 2 * i]);
        w3p[i] = *reinterpret_cast<const f32x2*>(&W3[(size_t)lane * NH + 2 * i]);
    }

    // ---- state (scalar per row: a,b,c,d) ----
    float m1a = 0.0f, t1a = 0.5f; bool s1a = false;
    float m1b = 0.0f, t1b = 0.5f; bool s1b = false;
    float m1c = 0.0f, t1c = 0.5f; bool s1c = false;
    float m1d = 0.0f, t1d = 0.5f; bool s1d = false;
    float m2a = 0.0f, t2a = 0.5f; bool s2a = false;
    float m2b = 0.0f, t2b = 0.5f; bool s2b = false;
    float m2c = 0.0f, t2c = 0.5f; bool s2c = false;
    float m2d = 0.0f, t2d = 0.5f; bool s2d = false;
    float m3a = 0.0f, t3a = 0.5f; bool s3a = false;
    float m3b = 0.0f, t3b = 0.5f; bool s3b = false;
    float m3c = 0.0f, t3c = 0.5f; bool s3c = false;
    float m3d = 0.0f, t3d = 0.5f; bool s3d = false;
    float c3fa = 0.0f, c3fb = 0.0f, c3fc = 0.0f, c3fd = 0.0f;

    const float* xra = input + (size_t)na * T_STEPS;     // wave-uniform
    const float* xrb = input + (size_t)nb * T_STEPS;
    const float* xrc = input + (size_t)nc * T_STEPS;
    const float* xrd = input + (size_t)nd * T_STEPS;
    const float* cerow = ce + (size_t)lane * T_STEPS;    // ce is [H][T]

    float xa_cur = xra[0], xb_cur = xrb[0], xc_cur = xrc[0], xd_cur = xrd[0];
    float co_cur = cerow[0];

#pragma unroll 1
    for (int t = 0; t < T_STEPS; ++t) {
        const int tn = (t < T_STEPS - 1) ? (t + 1) : (T_STEPS - 1);
        const float xa_nxt = xra[tn];
        const float xb_nxt = xrb[tn];
        const float xc_nxt = xrc[tn];
        const float xd_nxt = xrd[tn];
        const float co_nxt = cerow[tn];

        const float xa = xa_cur, xb = xb_cur, xc = xc_cur, xd = xd_cur;
        const float co = co_cur;

        // ================= layer 1 =================
        THUP(t1a, m1a) THUP(t1b, m1b) THUP(t1c, m1c) THUP(t1d, m1d)
        {
            const float ha = (xa * w1) + bb1; MEMUP(m1a, s1a, ha)
            const float hb = (xb * w1) + bb1; MEMUP(m1b, s1b, hb)
            const float hc = (xc * w1) + bb1; MEMUP(m1c, s1c, hc)
            const float hd = (xd * w1) + bb1; MEMUP(m1d, s1d, hd)
        }
        const bool p1a = m1a > t1a; s1a = p1a;
        const bool p1b = m1b > t1b; s1b = p1b;
        const bool p1c = m1c > t1c; s1c = p1c;
        const bool p1d = m1d > t1d; s1d = p1d;
        {
            f32x4 sv;
            sv.x = p1a ? 1.0f : 0.0f; sv.y = p1b ? 1.0f : 0.0f;
            sv.z = p1c ? 1.0f : 0.0f; sv.w = p1d ? 1.0f : 0.0f;
            sA4[lane] = sv;                              // ds_write_b128
        }

        // ================= layer 2 =================
        THUP(t2a, m2a) THUP(t2b, m2b) THUP(t2c, m2c) THUP(t2d, m2d)
        {
            f32x2 acc01; acc01.x = 0.0f; acc01.y = 0.0f;
            f32x2 acc23; acc23.x = 0.0f; acc23.y = 0.0f;
#pragma unroll
            for (int g = 0; g < 32; ++g) {
                const f32x4 qa = *reinterpret_cast<const f32x4*>(&sA4[2 * g]);     // k=2g
                const f32x4 qb = *reinterpret_cast<const f32x4*>(&sA4[2 * g + 1]); // k=2g+1
                f32x2 qa01; qa01.x = qa.x; qa01.y = qa.y;
                f32x2 qa23; qa23.x = qa.z; qa23.y = qa.w;
                f32x2 qb01; qb01.x = qb.x; qb01.y = qb.y;
                f32x2 qb23; qb23.x = qb.z; qb23.y = qb.w;
                PK_LO(acc01, qa01, w2p[g]);
                PK_LO(acc23, qa23, w2p[g]);
                PK_HI(acc01, qb01, w2p[g]);
                PK_HI(acc23, qb23, w2p[g]);
            }
            const float h2a = acc01.x + bb2; MEMUP(m2a, s2a, h2a)
            const float h2b = acc01.y + bb2; MEMUP(m2b, s2b, h2b)
            const float h2c = acc23.x + bb2; MEMUP(m2c, s2c, h2c)
            const float h2d = acc23.y + bb2; MEMUP(m2d, s2d, h2d)
        }
        const bool p2a = m2a > t2a; s2a = p2a;
        const bool p2b = m2b > t2b; s2b = p2b;
        const bool p2c = m2c > t2c; s2c = p2c;
        const bool p2d = m2d > t2d; s2d = p2d;
        {
            f32x4 sv;
            sv.x = p2a ? 1.0f : 0.0f; sv.y = p2b ? 1.0f : 0.0f;
            sv.z = p2c ? 1.0f : 0.0f; sv.w = p2d ? 1.0f : 0.0f;
            sB4[lane] = sv;
        }

        // ================= layer 3 =================
        THUP(t3a, m3a) THUP(t3b, m3b) THUP(t3c, m3c) THUP(t3d, m3d)
        {
            f32x2 acc01; acc01.x = 0.0f; acc01.y = 0.0f;
            f32x2 acc23; acc23.x = 0.0f; acc23.y = 0.0f;
#pragma unroll
            for (int g = 0; g < 32; ++g) {
                const f32x4 qa = *reinterpret_cast<const f32x4*>(&sB4[2 * g]);
                const f32x4 qb = *reinterpret_cast<const f32x4*>(&sB4[2 * g + 1]);
                f32x2 qa01; qa01.x = qa.x; qa01.y = qa.y;
                f32x2 qa23; qa23.x = qa.z; qa23.y = qa.w;
                f32x2 qb01; qb01.x = qb.x; qb01.y = qb.y;
                f32x2 qb23; qb23.x = qb.z; qb23.y = qb.w;
                PK_LO(acc01, qa01, w3p[g]);
                PK_LO(acc23, qa23, w3p[g]);
                PK_HI(acc01, qb01, w3p[g]);
                PK_HI(acc23, qb23, w3p[g]);
            }
            const float h3a = acc01.x + bb3; MEMUP(m3a, s3a, h3a)
            const float h3b = acc01.y + bb3; MEMUP(m3b, s3b, h3b)
            const float h3c = acc23.x + bb3; MEMUP(m3c, s3c, h3c)
            const float h3d = acc23.y + bb3; MEMUP(m3d, s3d, h3d)
        }
        const bool p3a = m3a > t3a; s3a = p3a;
        const bool p3b = m3b > t3b; s3b = p3b;
        const bool p3c = m3c > t3c; s3c = p3c;
        const bool p3d = m3d > t3d; s3d = p3d;
        c3fa += p3a ? 1.0f : 0.0f;
        c3fb += p3b ? 1.0f : 0.0f;
        c3fc += p3c ? 1.0f : 0.0f;
        c3fd += p3d ? 1.0f : 0.0f;

        xa_cur = xa_nxt; xb_cur = xb_nxt; xc_cur = xc_nxt; xd_cur = xd_nxt;
        co_cur = co_nxt;
    }

    // ---- epilogue: out[n][o] = (sum_t s3) @ Wo.T / T + bo ----
    const double cA = (double)c3fa, cB = (double)c3fb;
    const double cC = (double)c3fc, cD = (double)c3fd;
    double rA = 0.0, rB = 0.0, rC = 0.0, rD = 0.0;
#pragma unroll
    for (int o = 0; o < NOUT; ++o) {
        const double wo = (double)Wo[o * NH + lane];
        double vA = cA * wo, vB = cB * wo, vC = cC * wo, vD = cD * wo;
#pragma unroll
        for (int off = 32; off; off >>= 1) {
            vA += __shfl_xor(vA, off, 64);
            vB += __shfl_xor(vB, off, 64);
            vC += __shfl_xor(vC, off, 64);
            vD += __shfl_xor(vD, off, 64);
        }
        if (lane == o) { rA = vA; rB = vB; rC = vC; rD = vD; }
    }
    if (lane < NOUT) {
        const double bod = (double)bo[lane];
        out[(size_t)na * NOUT + lane] = (float)(rA / (double)T_STEPS + bod);
        if (n0 + 1 < N) out[(size_t)nb * NOUT + lane] = (float)(rB / (double)T_STEPS + bod);
        if (n0 + 2 < N) out[(size_t)nc * NOUT + lane] = (float)(rC / (double)T_STEPS + bod);
        if (n0 + 3 < N) out[(size_t)nd * NOUT + lane] = (float)(rD / (double)T_STEPS + bod);
    }
}

extern "C" void kernel_launch(void* const* d_in, const int* in_sizes, int n_in,
                              void* d_out, int out_size, void* d_ws, size_t ws_size,
                              hipStream_t stream) {
    const float* input = (const float*)d_in[0];
    const float* W1 = (const float*)d_in[1];
    const float* b1 = (const float*)d_in[2];
    const float* W2 = (const float*)d_in[3];
    const float* b2 = (const float*)d_in[4];
    const float* W3 = (const float*)d_in[5];
    const float* b3 = (const float*)d_in[6];
    const float* Wo = (const float*)d_in[7];
    const float* bo = (const float*)d_in[8];
    const float* ce = (const float*)d_in[9];
    float* out = (float*)d_out;

    const int N = in_sizes[0] / T_STEPS;

    hipLaunchKernelGGL(tesnn_main_kernel,
                       dim3((N + 3) / 4), dim3(64), 0, stream,
                       input, W1, b1, W2, b2, W3, b3, Wo, bo, ce, out, N);
}